// Round 1
// baseline (153.062 us; speedup 1.0000x reference)
//
#include <hip/hip_runtime.h>
#include <math.h>

#define NB 4
#define NT 1024
#define NH 27
#define NW 48
#define NPIX (NH * NW)      // 1296
#define NBINS 512
#define LOOKUP 101
#define PADW 50
#define ODIM 128
#define WIN_STRIDE 104      // padded row stride for win rows

// ---------------- Kernel A: per-frame 512-bin color histogram + L2 normalize
__global__ __launch_bounds__(256) void hist_kernel(const int* __restrict__ frames,
                                                   float* __restrict__ X) {
    const int frame = blockIdx.x;                       // b*NT + t
    const int* fp = frames + (size_t)frame * NPIX * 3;
    __shared__ unsigned int hist[NBINS];
    const int tid = threadIdx.x;

    for (int i = tid; i < NBINS; i += 256) hist[i] = 0u;
    __syncthreads();

    for (int p = tid; p < NPIX; p += 256) {
        int r = fp[p * 3 + 0];
        int g = fp[p * 3 + 1];
        int b = fp[p * 3 + 2];
        int bin = ((r >> 5) << 6) | ((g >> 5) << 3) | (b >> 5);
        atomicAdd(&hist[bin], 1u);
    }
    __syncthreads();

    // block-reduce sum of squares
    float local = 0.f;
    for (int i = tid; i < NBINS; i += 256) {
        float h = (float)hist[i];
        local += h * h;
    }
    for (int off = 32; off >= 1; off >>= 1)
        local += __shfl_xor(local, off, 64);
    __shared__ float wsum[4];
    if ((tid & 63) == 0) wsum[tid >> 6] = local;
    __syncthreads();
    float s = wsum[0] + wsum[1] + wsum[2] + wsum[3];
    float inv = 1.0f / fmaxf(sqrtf(s), 1e-12f);

    float* xp = X + (size_t)frame * NBINS;
    for (int i = tid; i < NBINS; i += 256) xp[i] = (float)hist[i] * inv;
}

// ---------------- Kernel B: banded similarities win[b,t,l] = <x_t, x_{t+l-50}>
__global__ __launch_bounds__(256) void sims_kernel(const float* __restrict__ X,
                                                   float* __restrict__ win) {
    const int frame = blockIdx.x;      // b*NT + t
    const int b = frame >> 10;
    const int t = frame & (NT - 1);
    const int tid = threadIdx.x;
    const int lane = tid & 63;
    const int wv = tid >> 6;           // 4 waves per block

    __shared__ __align__(16) float sx[NBINS];
    const float* xt = X + (size_t)frame * NBINS;
    for (int i = tid; i < NBINS; i += 256) sx[i] = xt[i];
    __syncthreads();

    float* wrow = win + (size_t)frame * WIN_STRIDE;
    const float4* sx4 = (const float4*)sx;

    for (int l = wv; l < LOOKUP; l += 4) {
        const int j = t + l - PADW;    // wave-uniform
        float dot = 0.f;
        if (j >= 0 && j < NT) {
            const float4* xj4 = (const float4*)(X + ((size_t)(b * NT + j)) * NBINS);
            float4 a0 = xj4[lane * 2 + 0];
            float4 a1 = xj4[lane * 2 + 1];
            float4 b0 = sx4[lane * 2 + 0];
            float4 b1 = sx4[lane * 2 + 1];
            dot = a0.x * b0.x + a0.y * b0.y + a0.z * b0.z + a0.w * b0.w
                + a1.x * b1.x + a1.y * b1.y + a1.z * b1.z + a1.w * b1.w;
            for (int off = 32; off >= 1; off >>= 1)
                dot += __shfl_xor(dot, off, 64);
        }
        if (lane == 0) wrow[l] = dot;
    }
}

// ---------------- Kernel C: out[b,t,o] = relu(sum_l win[b,t,l] * W[l,o] + bias[o])
__global__ __launch_bounds__(128) void fc_kernel(const float* __restrict__ win,
                                                 const float* __restrict__ w,
                                                 const float* __restrict__ bias,
                                                 float* __restrict__ out) {
    const int frame = blockIdx.x;
    const int tid = threadIdx.x;       // 0..127 = output channel
    __shared__ float swin[LOOKUP];
    const float* wrow = win + (size_t)frame * WIN_STRIDE;
    if (tid < LOOKUP) swin[tid] = wrow[tid];
    __syncthreads();

    float acc = bias[tid];
#pragma unroll 4
    for (int l = 0; l < LOOKUP; ++l)
        acc += swin[l] * w[l * ODIM + tid];
    out[(size_t)frame * ODIM + tid] = fmaxf(acc, 0.f);
}

extern "C" void kernel_launch(void* const* d_in, const int* in_sizes, int n_in,
                              void* d_out, int out_size, void* d_ws, size_t ws_size,
                              hipStream_t stream) {
    const int*   frames = (const int*)d_in[0];
    const float* fc_w   = (const float*)d_in[1];
    const float* fc_b   = (const float*)d_in[2];
    float* out = (float*)d_out;

    float* X   = (float*)d_ws;                          // 4096*512 f32 = 8 MB
    float* win = X + (size_t)NB * NT * NBINS;           // 4096*104 f32 ≈ 1.7 MB

    hist_kernel<<<NB * NT, 256, 0, stream>>>(frames, X);
    sims_kernel<<<NB * NT, 256, 0, stream>>>(X, win);
    fc_kernel  <<<NB * NT, 128, 0, stream>>>(win, fc_w, fc_b, out);
}

// Round 2
// 115.179 us; speedup vs baseline: 1.3289x; 1.3289x over previous
//
#include <hip/hip_runtime.h>
#include <math.h>

#define NB 4
#define NT 1024
#define NPIX 1296
#define NBINS 512
#define LOOKUP 101
#define PADW 50
#define ODIM 128

typedef _Float16 v2h __attribute__((ext_vector_type(2)));

__device__ inline float dot2(unsigned a, unsigned b, float acc) {
    union U { unsigned u; v2h h; } ua, ub;
    ua.u = a; ub.u = b;
#if __has_builtin(__builtin_amdgcn_fdot2)
    return __builtin_amdgcn_fdot2(ua.h, ub.h, acc, false);
#else
    return acc + (float)ua.h.x * (float)ub.h.x + (float)ua.h.y * (float)ub.h.y;
#endif
}

// ---------------- Kernel A: per-frame 512-bin histogram -> L2-normalized f16 row
__global__ __launch_bounds__(256) void hist_kernel(const int* __restrict__ frames,
                                                   unsigned short* __restrict__ X) {
    const int frame = blockIdx.x;
    const int tid = threadIdx.x;
    __shared__ unsigned int hist[NBINS];
    for (int i = tid; i < NBINS; i += 256) hist[i] = 0u;
    __syncthreads();

    // 1296 px * 3 ints = 972 int4; 4 pixels per 3 int4s
    const int4* f4 = (const int4*)(frames + (size_t)frame * NPIX * 3);
    for (int g = tid; g < NPIX / 4; g += 256) {   // 324 groups
        int4 a = f4[g * 3 + 0];
        int4 b = f4[g * 3 + 1];
        int4 c = f4[g * 3 + 2];
        int v[12] = {a.x, a.y, a.z, a.w, b.x, b.y, b.z, b.w, c.x, c.y, c.z, c.w};
#pragma unroll
        for (int p = 0; p < 4; ++p) {
            int bin = ((v[3 * p] >> 5) << 6) | ((v[3 * p + 1] >> 5) << 3) | (v[3 * p + 2] >> 5);
            atomicAdd(&hist[bin], 1u);
        }
    }
    __syncthreads();

    float local = 0.f;
    for (int i = tid; i < NBINS; i += 256) {
        float h = (float)hist[i];
        local += h * h;
    }
    for (int off = 32; off >= 1; off >>= 1) local += __shfl_xor(local, off, 64);
    __shared__ float wsum[4];
    if ((tid & 63) == 0) wsum[tid >> 6] = local;
    __syncthreads();
    float inv = 1.0f / fmaxf(sqrtf(wsum[0] + wsum[1] + wsum[2] + wsum[3]), 1e-12f);

    // pack bins 2*tid, 2*tid+1 into one dword, coalesced store
    unsigned* xrow = (unsigned*)(X + (size_t)frame * NBINS);
    union U { _Float16 h[2]; unsigned u; } pk;
    pk.h[0] = (_Float16)((float)hist[2 * tid] * inv);
    pk.h[1] = (_Float16)((float)hist[2 * tid + 1] * inv);
    xrow[tid] = pk.u;
}

// ---------------- Kernel B (fused): banded sims + FC + ReLU
// block = one frame t. 4 waves x 4 lane-groups of 16 -> 16 dots per round, 7 rounds.
__global__ __launch_bounds__(256) void simsfc_kernel(const unsigned short* __restrict__ X,
                                                     const float* __restrict__ w,
                                                     const float* __restrict__ bias,
                                                     float* __restrict__ out) {
    const int bid = blockIdx.x;
    // XCD swizzle: contiguous frame ranges land on one XCD -> X slice is L2-resident
    const int frame = ((bid & 7) << 9) | (bid >> 3);
    const int b = frame >> 10;
    const int t = frame & (NT - 1);
    const int tid = threadIdx.x;
    const int lane = tid & 63;
    const int wv = tid >> 6;          // 0..3
    const int grp = lane >> 4;        // 0..3
    const int kl = lane & 15;         // 0..15: k-slice within the group

    __shared__ __align__(16) uint4 sx[64];        // x_t: 512 f16 = 1 KB
    __shared__ float win[LOOKUP];
    __shared__ float pad[2][ODIM];

    const uint4* xt = (const uint4*)(X + (size_t)frame * NBINS);
    if (tid < 64) sx[tid] = xt[tid];
    __syncthreads();

    const unsigned short* Xb = X + (size_t)b * NT * NBINS;

    for (int r = 0; r < 7; ++r) {
        const int l = r * 16 + wv * 4 + grp;
        const int j = t + l - PADW;
        const bool valid = (l < LOOKUP) & (j >= 0) & (j < NT);
        const int jc = min(max(j, 0), NT - 1);
        const uint4* xj = (const uint4*)(Xb + (size_t)jc * NBINS);
        float a0 = 0.f, a1 = 0.f;
#pragma unroll
        for (int i = 0; i < 4; ++i) {
            uint4 A = xj[kl + 16 * i];    // 16 lanes -> contiguous 256 B per group
            uint4 S = sx[kl + 16 * i];    // broadcast across groups, 2-way banks
            a0 = dot2(A.x, S.x, a0);
            a1 = dot2(A.y, S.y, a1);
            a0 = dot2(A.z, S.z, a0);
            a1 = dot2(A.w, S.w, a1);
        }
        float s = a0 + a1;
        s += __shfl_xor(s, 1, 64);
        s += __shfl_xor(s, 2, 64);
        s += __shfl_xor(s, 4, 64);
        s += __shfl_xor(s, 8, 64);
        if (kl == 0 && l < LOOKUP) win[l] = valid ? s : 0.f;
    }
    __syncthreads();

    // FC: 256 threads = 2 halves x 128 channels
    const int ch = tid & 127;
    const int half = tid >> 7;
    float acc = half ? 0.f : bias[ch];
    const int l0 = half ? 51 : 0;
    const int l1 = half ? LOOKUP : 51;
#pragma unroll 4
    for (int l = l0; l < l1; ++l)
        acc = fmaf(win[l], w[l * ODIM + ch], acc);
    pad[half][ch] = acc;
    __syncthreads();
    if (tid < ODIM)
        out[(size_t)frame * ODIM + tid] = fmaxf(pad[0][tid] + pad[1][tid], 0.f);
}

extern "C" void kernel_launch(void* const* d_in, const int* in_sizes, int n_in,
                              void* d_out, int out_size, void* d_ws, size_t ws_size,
                              hipStream_t stream) {
    const int*   frames = (const int*)d_in[0];
    const float* fc_w   = (const float*)d_in[1];
    const float* fc_b   = (const float*)d_in[2];
    float* out = (float*)d_out;

    unsigned short* X = (unsigned short*)d_ws;   // 4096*512 f16 = 4 MB

    hist_kernel  <<<NB * NT, 256, 0, stream>>>(frames, X);
    simsfc_kernel<<<NB * NT, 256, 0, stream>>>(X, fc_w, fc_b, out);
}